// Round 16
// baseline (149.189 us; speedup 1.0000x reference)
//
#include <hip/hip_runtime.h>
#include <float.h>
#include <math.h>

#define NODE_DIM 256
#define HIDDEN   128
#define HEADS    8
#define HEAD_DIM 16
#define NB       768
#define BATCH    2
#define NNODES   (BATCH * NB)
#define SEP      776          // f16 row stride: 388 words, 388%32=4 (2-way, free)

typedef _Float16 f16;
typedef _Float16 h2 __attribute__((ext_vector_type(2)));
union F2H { float f; h2 h; unsigned u; };
union V4H { float4 f; h2 h[4]; };

// tanh-GELU, exp2-folded: g = u / (1 + exp2(u*(c1' + c3'*u^2)))
__device__ __forceinline__ float gelu_f(float u) {
  float u2 = u * u;
  float e  = __builtin_amdgcn_exp2f(u * fmaf(u2, -0.10294357f, -2.3022090f));
  return u * __builtin_amdgcn_rcpf(1.0f + e);
}

// == K1: QKV 8/block (0..191) + compaction (192,193) + P (194) + WoP (195) ====
__global__ __launch_bounds__(256) void prep_kernel(
    const float* __restrict__ nf, const float* __restrict__ pos,
    const int* __restrict__ mask,
    const float* __restrict__ Wq, const float* __restrict__ Wk,
    const float* __restrict__ Wv, const float* __restrict__ W1,
    const float* __restrict__ b1, const float* __restrict__ W2,
    const float* __restrict__ b2, const float* __restrict__ Wo,
    float* __restrict__ qc, f16* __restrict__ kTcH, f16* __restrict__ vcH,
    unsigned* __restrict__ WoP,
    float* __restrict__ P, float* __restrict__ b2m,
    float* __restrict__ pcx, float* __restrict__ pcy,
    int* __restrict__ vlist, int* __restrict__ mlist, int* __restrict__ cnt) {
  int blk = blockIdx.x, t = threadIdx.x;

  if (blk < NNODES / 8) {
    // ---- QKV for nodes n0..n0+7, local stable-prefix cidx ----
    int n0 = blk * 8;
    int b = n0 / NB;
    int lo = n0 - b * NB;
    __shared__ int accv;
    if (t == 0) accv = 0;
    __syncthreads();
    for (int jb = 0; jb < lo; jb += 256) {
      int j = jb + t;
      int mv = (j < lo) && (mask[b * NB + j] != 0);
      unsigned long long ball = __ballot(mv);
      if ((t & 63) == 0) atomicAdd(&accv, __popcll(ball));
    }
    __syncthreads();
    int cb = accv;
    int mv8[8], civ[8];
    int run = cb;
#pragma unroll
    for (int n = 0; n < 8; ++n) {
      mv8[n] = mask[n0 + n] != 0;
      civ[n] = run;
      run += mv8[n];
    }
    const float* xp[8];
#pragma unroll
    for (int n = 0; n < 8; ++n) xp[n] = nf + (size_t)(n0 + n) * NODE_DIM;

    for (int id = t; id < 3 * HIDDEN; id += 256) {
      int m = id >> 7, c = id & 127;
      const float* W = (m == 0) ? Wq : (m == 1) ? Wk : Wv;
      float acc[8] = {0.f, 0.f, 0.f, 0.f, 0.f, 0.f, 0.f, 0.f};
#pragma unroll 4
      for (int kk = 0; kk < NODE_DIM; kk += 2) {
        float w0 = W[kk * HIDDEN + c];             // coalesced
        float w1 = W[(kk + 1) * HIDDEN + c];
#pragma unroll
        for (int n = 0; n < 8; ++n) {              // x: uniform -> s_load
          acc[n] = fmaf(xp[n][kk], w0, acc[n]);
          acc[n] = fmaf(xp[n][kk + 1], w1, acc[n]);
        }
      }
#pragma unroll
      for (int n = 0; n < 8; ++n) {
        if (mv8[n]) {
          int slot = b * NB + civ[n];
          if (m == 0)      qc[(size_t)slot * HIDDEN + c] = acc[n];
          else if (m == 1) kTcH[((size_t)b * HIDDEN + c) * NB + civ[n]] = (f16)acc[n];
          else             vcH[(size_t)slot * HIDDEN + c] = (f16)acc[n];
        }
      }
    }
  } else if (blk < NNODES / 8 + 2) {
    // ---- stable (ascending-j) compaction for batch b ----
    int b = blk - NNODES / 8;
    __shared__ int wcnt[4];
    __shared__ int base2[2];
    if (t < 2) base2[t] = 0;
    __syncthreads();
    int lane = t & 63, w = t >> 6;
    for (int iter = 0; iter < NB / 256; ++iter) {
      int j = iter * 256 + t;
      int mv = mask[b * NB + j] != 0;
      unsigned long long ball = __ballot(mv);
      if (lane == 0) wcnt[w] = __popcll(ball);
      __syncthreads();
      int pv = 0;
      for (int i = 0; i < w; ++i) pv += wcnt[i];
      int pin = (lane == 0) ? 0 : __popcll(ball & (~0ull >> (64 - lane)));
      if (mv) {
        int p = base2[0] + pv + pin;
        vlist[b * NB + p] = j;
        pcx[b * NB + p] = pos[(b * NB + j) * 2];
        pcy[b * NB + p] = pos[(b * NB + j) * 2 + 1];
      } else {
        int pm = base2[1] + (w * 64 - pv) + (lane - pin);
        mlist[b * NB + pm] = j;
      }
      __syncthreads();
      if (t == 0) {
        int tot = wcnt[0] + wcnt[1] + wcnt[2] + wcnt[3];
        base2[0] += tot;
        base2[1] += 256 - tot;
      }
      __syncthreads();
    }
    int nv = base2[0];
    if (t == 0) cnt[b] = nv;
    int nvp8 = (nv + 7) & ~7;             // zero-pad kTcH for f16x8 reads
    if (t < HIDDEN)
      for (int col = nv; col < nvp8; ++col)
        kTcH[((size_t)b * HIDDEN + t) * NB + col] = (f16)0.0f;
  } else if (blk == NNODES / 8 + 2) {
    // ---- pack P + b2m ----
    __shared__ float w2s[HIDDEN * HEADS];
    for (int idx = t; idx < HIDDEN * HEADS; idx += 256) {
      int c = idx >> 3, h = idx & 7;
      float s = 0.0f;
      for (int d = 0; d < HEAD_DIM; ++d) s += W2[c * HIDDEN + h * HEAD_DIM + d];
      w2s[idx] = s * (1.0f / 16.0f);
    }
    if (t < HEADS) {
      float s = 0.0f;
      for (int d = 0; d < HEAD_DIM; ++d) s += b2[t * HEAD_DIM + d];
      b2m[t] = s * (1.0f / 16.0f);
    }
    __syncthreads();
    if (t < HIDDEN) {
      float* Pr = P + t * 8;
      Pr[0] = W1[t];
      Pr[1] = W1[HIDDEN + t];
      Pr[2] = W1[2 * HIDDEN + t];
      Pr[3] = b1[t];
      f16* ph = (f16*)(Pr + 4);
#pragma unroll
      for (int h = 0; h < HEADS; ++h) ph[h] = (f16)w2s[t * 8 + h];
    }
  } else {
    // ---- pack Wo as f16 row-pairs ----
    for (int k2 = 0; k2 < 64; ++k2) {
      F2H w;
      w.h = (h2){(f16)Wo[(2 * k2) * NODE_DIM + t],
                 (f16)Wo[(2 * k2 + 1) * NODE_DIM + t]};
      WoP[k2 * 256 + t] = w.u;
    }
  }
}

// =============== K2: attention + out-proj + LayerNorm, 1 block/(b,ci) ========
__global__ __launch_bounds__(256) void attn_kernel(
    const float* __restrict__ pcx, const float* __restrict__ pcy,
    const int* __restrict__ cnt, const int* __restrict__ vlist,
    const int* __restrict__ mlist, const float* __restrict__ P,
    const float* __restrict__ b2m, const float* __restrict__ qc,
    const f16* __restrict__ kTcH, const f16* __restrict__ vcH,
    const unsigned* __restrict__ WoP,
    const float* __restrict__ nf, const float* __restrict__ bo,
    const float* __restrict__ gamma, const float* __restrict__ beta,
    float* __restrict__ out) {
  int b = blockIdx.x & 1, ci = blockIdx.x >> 1;
  int t = threadIdx.x;
  int nv = cnt[b];
  if (ci >= nv) {                      // masked node -> x==0 -> LN gives beta
    int node = b * NB + mlist[b * NB + (ci - nv)];
    out[(size_t)node * NODE_DIM + t] = beta[t];
    return;
  }
  int node = b * NB + vlist[b * NB + ci];
  int slot = b * NB + ci;

  __shared__ __align__(16) unsigned char smem[17600];
  f16*   sE     = (f16*)smem;                   // [8][SEP]   12416 B
  float* qs     = (float*)(smem + 12416);       // 512 B
  f16*   partDH = (f16*)(smem + 12928);         // [16][128]  4096 B
  float* aggL   = (float*)(smem + 17024);       // 512 B
  float* red    = (float*)(smem + 17536);       // 32 B
  float* invs   = (float*)(smem + 17568);       // 32 B

  if (t < HIDDEN) qs[t] = qc[(size_t)slot * HIDDEN + t];
  float pix = pcx[slot], piy = pcy[slot];
  __syncthreads();

  // ---- A: qk dots, f16x8 keys per iter (8 heads x 32 lanes), pk_fma ----
  {
    int h = t >> 5, l = t & 31;
    const f16* kb = kTcH + ((size_t)b * HIDDEN + h * 16) * NB;
    h2 qp[16];
#pragma unroll
    for (int r = 0; r < 16; ++r) {
      f16 qh = (f16)qs[h * 16 + r];
      qp[r] = (h2){qh, qh};
    }
    h2 sc4 = {(f16)0.25f, (f16)0.25f};
    f16 bhh = (f16)b2m[h];
    h2 bh2 = {bhh, bhh};
    int n8 = (nv + 7) >> 3;
    for (int j8 = l; j8 < n8; j8 += 32) {
      h2 acc[4] = {{0, 0}, {0, 0}, {0, 0}, {0, 0}};
#pragma unroll
      for (int r = 0; r < 16; ++r) {
        V4H kv;
        kv.f = *(const float4*)(kb + (size_t)r * NB + j8 * 8);
        acc[0] += qp[r] * kv.h[0];
        acc[1] += qp[r] * kv.h[1];
        acc[2] += qp[r] * kv.h[2];
        acc[3] += qp[r] * kv.h[3];
      }
      V4H res;
#pragma unroll
      for (int p = 0; p < 4; ++p) res.h[p] = acc[p] * sc4 + bh2;
      *(float4*)(sE + h * SEP + j8 * 8) = res.f;
    }
  }
  __syncthreads();

  // ---- B: edge-MLP bias; guarded per-slot passes ----
#pragma unroll
  for (int sl = 0; sl < 3; ++sl) {
    int k0 = t + sl * 256;
    if (k0 < nv) {
      int s0 = b * NB + k0;
      float dx = pix - pcx[s0], dy = piy - pcy[s0];
      float sq = fmaf(dx, dx, dy * dy);
      float dist = __builtin_amdgcn_sqrtf(sq + 1e-6f);
      float inv  = fminf(__builtin_amdgcn_rsqf(sq), 1e6f);
      float ux = dx * inv, uy = dy * inv;
      h2 bacc[4] = {{0, 0}, {0, 0}, {0, 0}, {0, 0}};
#pragma unroll 4
      for (int c = 0; c < HIDDEN; ++c) {
        const float4* Pc = (const float4*)(P + c * 8);   // uniform -> s_load
        float4 p0 = Pc[0], pw = Pc[1];
        float g = gelu_f(fmaf(ux, p0.x, fmaf(uy, p0.y, fmaf(dist, p0.z, p0.w))));
        f16 gh = (f16)g;
        h2 gg = {gh, gh};
        F2H w0, w1, w2, w3;
        w0.f = pw.x; w1.f = pw.y; w2.f = pw.z; w3.f = pw.w;
        bacc[0] += gg * w0.h;
        bacc[1] += gg * w1.h;
        bacc[2] += gg * w2.h;
        bacc[3] += gg * w3.h;
      }
      f16* row = sE + k0;
#pragma unroll
      for (int p = 0; p < 4; ++p) {
        row[(2 * p + 0) * SEP] = (f16)(row[(2 * p + 0) * SEP] + bacc[p].x);
        row[(2 * p + 1) * SEP] = (f16)(row[(2 * p + 1) * SEP] + bacc[p].y);
      }
    }
  }
  __syncthreads();

  // ---- C: softmax denom WITHOUT max-sub (|score| <~ 6 -> exp safe) ----
  {
    int h = t >> 5, l = t & 31;
    f16* row = sE + h * SEP;
    float s = 0.0f;
    for (int jj = l; jj < nv; jj += 32) {
      float e = __expf((float)row[jj]);
      row[jj] = (f16)e;
      s += e;
    }
    for (int off = 16; off; off >>= 1) s += __shfl_down(s, off, 32);
    if (l == 0) invs[h] = 1.0f / s;
  }
  __syncthreads();

  // ---- D: weighted V, f16x8 channels x 16 key-groups, pk_fma; f16 partials ---
  {
    int o8 = t & 15, g = t >> 4;       // 16 channel-groups x 16 key-groups
    int h = o8 >> 1;
    h2 acc[4] = {{0, 0}, {0, 0}, {0, 0}, {0, 0}};
    for (int jj = g; jj < nv; jj += 16) {
      V4H vv;
      vv.f = *(const float4*)(vcH + (size_t)(b * NB + jj) * HIDDEN + o8 * 8);
      f16 w = sE[h * SEP + jj];
      h2 ww = {w, w};
      acc[0] += ww * vv.h[0];
      acc[1] += ww * vv.h[1];
      acc[2] += ww * vv.h[2];
      acc[3] += ww * vv.h[3];
    }
    V4H res;
#pragma unroll
    for (int p = 0; p < 4; ++p) res.h[p] = acc[p];
    *(float4*)(partDH + g * HIDDEN + o8 * 8) = res.f;
  }
  __syncthreads();
  if (t < HIDDEN) {
    float s = 0.0f;
#pragma unroll
    for (int g = 0; g < 16; ++g) s += (float)partDH[g * HIDDEN + t];
    aggL[t] = s * invs[t >> 4];
  }
  __syncthreads();

  // ---- E: out projection (f16 packed row-pairs) + residual + LayerNorm ----
  {
    float y0 = bo[t], y1 = 0.f;
    const unsigned* wp = WoP + t;
    const float2* a2 = (const float2*)aggL;
#pragma unroll 4
    for (int k2 = 0; k2 < 64; ++k2) {
      F2H w;
      w.u = wp[(size_t)k2 * 256];                 // coalesced 4B
      float2 a = a2[k2];                          // ds_read_b64 broadcast
      y0 = fmaf(a.x, (float)w.h.x, y0);
      y1 = fmaf(a.y, (float)w.h.y, y1);
    }
    float y = y0 + y1;
    float xv = nf[(size_t)node * NODE_DIM + t] + y;
    float s = xv, s2 = xv * xv;
    for (int off = 32; off; off >>= 1) {
      s += __shfl_down(s, off, 64);
      s2 += __shfl_down(s2, off, 64);
    }
    if ((t & 63) == 0) { red[t >> 6] = s; red[4 + (t >> 6)] = s2; }
    __syncthreads();
    s  = red[0] + red[1] + red[2] + red[3];
    s2 = red[4] + red[5] + red[6] + red[7];
    float mu = s * (1.0f / NODE_DIM);
    float var = fmaxf(s2 * (1.0f / NODE_DIM) - mu * mu, 0.0f);
    out[(size_t)node * NODE_DIM + t] =
        (xv - mu) * rsqrtf(var + 1e-5f) * gamma[t] + beta[t];
  }
}

extern "C" void kernel_launch(void* const* d_in, const int* in_sizes, int n_in,
                              void* d_out, int out_size, void* d_ws, size_t ws_size,
                              hipStream_t stream) {
  const float* nf    = (const float*)d_in[0];
  const float* pos   = (const float*)d_in[1];
  const int*   mask  = (const int*)  d_in[2];
  const float* Wq    = (const float*)d_in[3];
  const float* Wk    = (const float*)d_in[4];
  const float* Wv    = (const float*)d_in[5];
  const float* W1    = (const float*)d_in[6];
  const float* b1    = (const float*)d_in[7];
  const float* W2    = (const float*)d_in[8];
  const float* b2    = (const float*)d_in[9];
  const float* Wo    = (const float*)d_in[10];
  const float* bo    = (const float*)d_in[11];
  const float* gamma = (const float*)d_in[12];
  const float* beta  = (const float*)d_in[13];

  const int QKV = NNODES * HIDDEN;            // 196608

  float*    ws   = (float*)d_ws;
  float*    qc   = ws;
  f16*      kTcH = (f16*)(qc + QKV);
  f16*      vcH  = kTcH + QKV;
  unsigned* WoP  = (unsigned*)(vcH + QKV);
  float*    P    = (float*)(WoP + 64 * 256);
  float*    b2m  = P + HIDDEN * 8;
  float*    pcx  = b2m + 8;
  float*    pcy  = pcx + NNODES;
  int*      vlist= (int*)(pcy + NNODES);
  int*      mlist= vlist + NNODES;
  int*      cnt  = mlist + NNODES;

  prep_kernel<<<NNODES / 8 + 4, 256, 0, stream>>>(
      nf, pos, mask, Wq, Wk, Wv, W1, b1, W2, b2, Wo,
      qc, kTcH, vcH, WoP, P, b2m, pcx, pcy, vlist, mlist, cnt);
  attn_kernel<<<NNODES, 256, 0, stream>>>(
      pcx, pcy, cnt, vlist, mlist, P, b2m, qc, kTcH, vcH, WoP,
      nf, bo, gamma, beta, (float*)d_out);
}

// Round 17
// 135.595 us; speedup vs baseline: 1.1003x; 1.1003x over previous
//
#include <hip/hip_runtime.h>
#include <float.h>
#include <math.h>

#define NODE_DIM 256
#define HIDDEN   128
#define HEADS    8
#define HEAD_DIM 16
#define NB       768
#define BATCH    2
#define NNODES   (BATCH * NB)
#define SEP      776          // f16 row stride: 388 words, 388%32=4 (2-way, free)

typedef _Float16 f16;
typedef _Float16 h2 __attribute__((ext_vector_type(2)));
union F2H { float f; h2 h; unsigned u; };
union V4H { float4 f; h2 h[4]; };

// tanh-GELU, exp2-folded: g = u / (1 + exp2(u*(c1' + c3'*u^2)))
__device__ __forceinline__ float gelu_f(float u) {
  float u2 = u * u;
  float e  = __builtin_amdgcn_exp2f(u * fmaf(u2, -0.10294357f, -2.3022090f));
  return u * __builtin_amdgcn_rcpf(1.0f + e);
}

// == K1: QKV (blocks 0..383) + compaction (384,385) + P (386) + WoP (387) =====
__global__ __launch_bounds__(256) void prep_kernel(
    const float* __restrict__ nf, const float* __restrict__ pos,
    const int* __restrict__ mask,
    const float* __restrict__ Wq, const float* __restrict__ Wk,
    const float* __restrict__ Wv, const float* __restrict__ W1,
    const float* __restrict__ b1, const float* __restrict__ W2,
    const float* __restrict__ b2, const float* __restrict__ Wo,
    float* __restrict__ qc, f16* __restrict__ kTcH, f16* __restrict__ vcH,
    unsigned* __restrict__ WoP,
    float* __restrict__ P, float* __restrict__ b2m,
    float* __restrict__ pcx, float* __restrict__ pcy,
    int* __restrict__ vlist, int* __restrict__ mlist, int* __restrict__ cnt) {
  int blk = blockIdx.x, t = threadIdx.x;

  if (blk < NNODES / 4) {
    int n0 = blk * 4;
    int b = n0 / NB;
    int lo = n0 - b * NB;
    __shared__ int accv;
    if (t == 0) accv = 0;
    __syncthreads();
    for (int jb = 0; jb < lo; jb += 256) {
      int j = jb + t;
      int mv = (j < lo) && (mask[b * NB + j] != 0);
      unsigned long long ball = __ballot(mv);
      if ((t & 63) == 0) atomicAdd(&accv, __popcll(ball));
    }
    __syncthreads();
    int cb = accv;
    int m0 = mask[n0] != 0, m1 = mask[n0 + 1] != 0, m2 = mask[n0 + 2] != 0,
        m3 = mask[n0 + 3] != 0;
    int civ[4] = {cb, cb + m0, cb + m0 + m1, cb + m0 + m1 + m2};
    int mv4[4] = {m0, m1, m2, m3};

    const float* x0 = nf + (size_t)(n0 + 0) * NODE_DIM;
    const float* x1 = nf + (size_t)(n0 + 1) * NODE_DIM;
    const float* x2 = nf + (size_t)(n0 + 2) * NODE_DIM;
    const float* x3 = nf + (size_t)(n0 + 3) * NODE_DIM;
    for (int id = t; id < 3 * HIDDEN; id += 256) {
      int m = id >> 7, c = id & 127;
      const float* W = (m == 0) ? Wq : (m == 1) ? Wk : Wv;
      float a0 = 0.f, a1 = 0.f, a2 = 0.f, a3 = 0.f;
      float e0 = 0.f, e1 = 0.f, e2 = 0.f, e3 = 0.f;
#pragma unroll 8
      for (int kk = 0; kk < NODE_DIM; kk += 2) {
        float w0 = W[kk * HIDDEN + c];
        float w1 = W[(kk + 1) * HIDDEN + c];
        a0 = fmaf(x0[kk], w0, a0);  e0 = fmaf(x0[kk + 1], w1, e0);
        a1 = fmaf(x1[kk], w0, a1);  e1 = fmaf(x1[kk + 1], w1, e1);
        a2 = fmaf(x2[kk], w0, a2);  e2 = fmaf(x2[kk + 1], w1, e2);
        a3 = fmaf(x3[kk], w0, a3);  e3 = fmaf(x3[kk + 1], w1, e3);
      }
      float acc[4] = {a0 + e0, a1 + e1, a2 + e2, a3 + e3};
#pragma unroll
      for (int n = 0; n < 4; ++n) {
        if (mv4[n]) {
          int slot = b * NB + civ[n];
          if (m == 0)      qc[(size_t)slot * HIDDEN + c] = acc[n];
          else if (m == 1) kTcH[((size_t)b * HIDDEN + c) * NB + civ[n]] = (f16)acc[n];
          else             vcH[(size_t)slot * HIDDEN + c] = (f16)acc[n];
        }
      }
    }
  } else if (blk < NNODES / 4 + 2) {
    int b = blk - NNODES / 4;
    __shared__ int wcnt[4];
    __shared__ int base2[2];
    if (t < 2) base2[t] = 0;
    __syncthreads();
    int lane = t & 63, w = t >> 6;
    for (int iter = 0; iter < NB / 256; ++iter) {
      int j = iter * 256 + t;
      int mv = mask[b * NB + j] != 0;
      unsigned long long ball = __ballot(mv);
      if (lane == 0) wcnt[w] = __popcll(ball);
      __syncthreads();
      int pv = 0;
      for (int i = 0; i < w; ++i) pv += wcnt[i];
      int pin = (lane == 0) ? 0 : __popcll(ball & (~0ull >> (64 - lane)));
      if (mv) {
        int p = base2[0] + pv + pin;
        vlist[b * NB + p] = j;
        pcx[b * NB + p] = pos[(b * NB + j) * 2];
        pcy[b * NB + p] = pos[(b * NB + j) * 2 + 1];
      } else {
        int pm = base2[1] + (w * 64 - pv) + (lane - pin);
        mlist[b * NB + pm] = j;
      }
      __syncthreads();
      if (t == 0) {
        int tot = wcnt[0] + wcnt[1] + wcnt[2] + wcnt[3];
        base2[0] += tot;
        base2[1] += 256 - tot;
      }
      __syncthreads();
    }
    int nv = base2[0];
    if (t == 0) cnt[b] = nv;
    int nvp8 = (nv + 7) & ~7;
    if (t < HIDDEN)
      for (int col = nv; col < nvp8; ++col)
        kTcH[((size_t)b * HIDDEN + t) * NB + col] = (f16)0.0f;
  } else if (blk == NNODES / 4 + 2) {
    __shared__ float w2s[HIDDEN * HEADS];
    for (int idx = t; idx < HIDDEN * HEADS; idx += 256) {
      int c = idx >> 3, h = idx & 7;
      float s = 0.0f;
      for (int d = 0; d < HEAD_DIM; ++d) s += W2[c * HIDDEN + h * HEAD_DIM + d];
      w2s[idx] = s * (1.0f / 16.0f);
    }
    if (t < HEADS) {
      float s = 0.0f;
      for (int d = 0; d < HEAD_DIM; ++d) s += b2[t * HEAD_DIM + d];
      b2m[t] = s * (1.0f / 16.0f);
    }
    __syncthreads();
    if (t < HIDDEN) {
      float* Pr = P + t * 8;
      Pr[0] = W1[t];
      Pr[1] = W1[HIDDEN + t];
      Pr[2] = W1[2 * HIDDEN + t];
      Pr[3] = b1[t];
      f16* ph = (f16*)(Pr + 4);
#pragma unroll
      for (int h = 0; h < HEADS; ++h) ph[h] = (f16)w2s[t * 8 + h];
    }
  } else {
    for (int k2 = 0; k2 < 64; ++k2) {
      F2H w;
      w.h = (h2){(f16)Wo[(2 * k2) * NODE_DIM + t],
                 (f16)Wo[(2 * k2 + 1) * NODE_DIM + t]};
      WoP[k2 * 256 + t] = w.u;
    }
  }
}

// =============== K2: attention + out-proj + LayerNorm, 1 block/(b,ci) ========
__global__ __launch_bounds__(256) void attn_kernel(
    const float* __restrict__ pcx, const float* __restrict__ pcy,
    const int* __restrict__ cnt, const int* __restrict__ vlist,
    const int* __restrict__ mlist, const float* __restrict__ P,
    const float* __restrict__ b2m, const float* __restrict__ qc,
    const f16* __restrict__ kTcH, const f16* __restrict__ vcH,
    const unsigned* __restrict__ WoP,
    const float* __restrict__ nf, const float* __restrict__ bo,
    const float* __restrict__ gamma, const float* __restrict__ beta,
    float* __restrict__ out) {
  int b = blockIdx.x & 1, ci = blockIdx.x >> 1;
  int t = threadIdx.x;
  int nv = cnt[b];
  if (ci >= nv) {                      // masked node -> x==0 -> LN gives beta
    int node = b * NB + mlist[b * NB + (ci - nv)];
    out[(size_t)node * NODE_DIM + t] = beta[t];
    return;
  }
  int node = b * NB + vlist[b * NB + ci];
  int slot = b * NB + ci;

  __shared__ __align__(16) unsigned char smem[21760];
  f16*   sE    = (f16*)smem;                   // [8][SEP]   12416 B
  float* qs    = (float*)(smem + 12416);       // 512 B
  float* partD = (float*)(smem + 12928);       // [16][128]  8192 B
  float* aggL  = (float*)(smem + 21120);       // 512 B
  float* red   = (float*)(smem + 21632);       // 32 B
  float* invs  = (float*)(smem + 21664);       // 32 B

  if (t < HIDDEN) qs[t] = qc[(size_t)slot * HIDDEN + t];
  float pix = pcx[slot], piy = pcy[slot];
  __syncthreads();

  // ---- A: qk dots, f16x8 keys per iter (8 heads x 32 lanes), pk_fma ----
  {
    int h = t >> 5, l = t & 31;
    const f16* kb = kTcH + ((size_t)b * HIDDEN + h * 16) * NB;
    h2 qp[16];
#pragma unroll
    for (int r = 0; r < 16; ++r) {
      f16 qh = (f16)qs[h * 16 + r];
      qp[r] = (h2){qh, qh};
    }
    h2 sc4 = {(f16)0.25f, (f16)0.25f};
    f16 bhh = (f16)b2m[h];
    h2 bh2 = {bhh, bhh};
    int n8 = (nv + 7) >> 3;
    for (int j8 = l; j8 < n8; j8 += 32) {
      h2 acc[4] = {{0, 0}, {0, 0}, {0, 0}, {0, 0}};
#pragma unroll
      for (int r = 0; r < 16; ++r) {
        V4H kv;
        kv.f = *(const float4*)(kb + (size_t)r * NB + j8 * 8);
        acc[0] += qp[r] * kv.h[0];
        acc[1] += qp[r] * kv.h[1];
        acc[2] += qp[r] * kv.h[2];
        acc[3] += qp[r] * kv.h[3];
      }
      V4H res;
#pragma unroll
      for (int p = 0; p < 4; ++p) res.h[p] = acc[p] * sc4 + bh2;
      *(float4*)(sE + h * SEP + j8 * 8) = res.f;
    }
  }
  __syncthreads();

  // ---- B: edge-MLP bias; guarded per-slot passes ----
#pragma unroll
  for (int sl = 0; sl < 3; ++sl) {
    int k0 = t + sl * 256;
    if (k0 < nv) {
      int s0 = b * NB + k0;
      float dx = pix - pcx[s0], dy = piy - pcy[s0];
      float sq = fmaf(dx, dx, dy * dy);
      float dist = __builtin_amdgcn_sqrtf(sq + 1e-6f);
      float inv  = fminf(__builtin_amdgcn_rsqf(sq), 1e6f);
      float ux = dx * inv, uy = dy * inv;
      h2 bacc[4] = {{0, 0}, {0, 0}, {0, 0}, {0, 0}};
#pragma unroll 4
      for (int c = 0; c < HIDDEN; ++c) {
        const float4* Pc = (const float4*)(P + c * 8);   // uniform -> s_load
        float4 p0 = Pc[0], pw = Pc[1];
        float g = gelu_f(fmaf(ux, p0.x, fmaf(uy, p0.y, fmaf(dist, p0.z, p0.w))));
        f16 gh = (f16)g;
        h2 gg = {gh, gh};
        F2H w0, w1, w2, w3;
        w0.f = pw.x; w1.f = pw.y; w2.f = pw.z; w3.f = pw.w;
        bacc[0] += gg * w0.h;
        bacc[1] += gg * w1.h;
        bacc[2] += gg * w2.h;
        bacc[3] += gg * w3.h;
      }
      f16* row = sE + k0;
#pragma unroll
      for (int p = 0; p < 4; ++p) {
        row[(2 * p + 0) * SEP] = (f16)(row[(2 * p + 0) * SEP] + bacc[p].x);
        row[(2 * p + 1) * SEP] = (f16)(row[(2 * p + 1) * SEP] + bacc[p].y);
      }
    }
  }
  __syncthreads();

  // ---- C: softmax per head (8 groups x 32 lanes) ----
  {
    int h = t >> 5, l = t & 31;
    f16* row = sE + h * SEP;
    float m = -FLT_MAX;
    for (int jj = l; jj < nv; jj += 32) m = fmaxf(m, (float)row[jj]);
    for (int off = 16; off; off >>= 1) m = fmaxf(m, __shfl_down(m, off, 32));
    m = __shfl(m, 0, 32);
    float s = 0.0f;
    for (int jj = l; jj < nv; jj += 32) {
      float e = __expf((float)row[jj] - m);
      row[jj] = (f16)e;
      s += e;
    }
    for (int off = 16; off; off >>= 1) s += __shfl_down(s, off, 32);
    if (l == 0) invs[h] = 1.0f / s;
  }
  __syncthreads();

  // ---- D: weighted V, f16x8 channels x 16 key-groups, pk_fma ----
  {
    int o8 = t & 15, g = t >> 4;       // 16 channel-groups x 16 key-groups
    int h = o8 >> 1;
    h2 acc[4] = {{0, 0}, {0, 0}, {0, 0}, {0, 0}};
    for (int jj = g; jj < nv; jj += 16) {
      V4H vv;
      vv.f = *(const float4*)(vcH + (size_t)(b * NB + jj) * HIDDEN + o8 * 8);
      f16 w = sE[h * SEP + jj];
      h2 ww = {w, w};
      acc[0] += ww * vv.h[0];
      acc[1] += ww * vv.h[1];
      acc[2] += ww * vv.h[2];
      acc[3] += ww * vv.h[3];
    }
    float* pd = partD + g * HIDDEN + o8 * 8;
    pd[0] = (float)acc[0].x; pd[1] = (float)acc[0].y;
    pd[2] = (float)acc[1].x; pd[3] = (float)acc[1].y;
    pd[4] = (float)acc[2].x; pd[5] = (float)acc[2].y;
    pd[6] = (float)acc[3].x; pd[7] = (float)acc[3].y;
  }
  __syncthreads();
  if (t < HIDDEN) {
    float s = 0.0f;
#pragma unroll
    for (int g = 0; g < 16; ++g) s += partD[g * HIDDEN + t];
    aggL[t] = s * invs[t >> 4];
  }
  __syncthreads();

  // ---- E: out projection (f16 packed row-pairs) + residual + LayerNorm ----
  {
    float y0 = bo[t], y1 = 0.f;
    const unsigned* wp = WoP + t;
    const float2* a2 = (const float2*)aggL;
#pragma unroll 4
    for (int k2 = 0; k2 < 64; ++k2) {
      F2H w;
      w.u = wp[(size_t)k2 * 256];                 // coalesced 4B
      float2 a = a2[k2];                          // ds_read_b64 broadcast
      y0 = fmaf(a.x, (float)w.h.x, y0);
      y1 = fmaf(a.y, (float)w.h.y, y1);
    }
    float y = y0 + y1;
    float xv = nf[(size_t)node * NODE_DIM + t] + y;
    float s = xv, s2 = xv * xv;
    for (int off = 32; off; off >>= 1) {
      s += __shfl_down(s, off, 64);
      s2 += __shfl_down(s2, off, 64);
    }
    if ((t & 63) == 0) { red[t >> 6] = s; red[4 + (t >> 6)] = s2; }
    __syncthreads();
    s  = red[0] + red[1] + red[2] + red[3];
    s2 = red[4] + red[5] + red[6] + red[7];
    float mu = s * (1.0f / NODE_DIM);
    float var = fmaxf(s2 * (1.0f / NODE_DIM) - mu * mu, 0.0f);
    out[(size_t)node * NODE_DIM + t] =
        (xv - mu) * rsqrtf(var + 1e-5f) * gamma[t] + beta[t];
  }
}

extern "C" void kernel_launch(void* const* d_in, const int* in_sizes, int n_in,
                              void* d_out, int out_size, void* d_ws, size_t ws_size,
                              hipStream_t stream) {
  const float* nf    = (const float*)d_in[0];
  const float* pos   = (const float*)d_in[1];
  const int*   mask  = (const int*)  d_in[2];
  const float* Wq    = (const float*)d_in[3];
  const float* Wk    = (const float*)d_in[4];
  const float* Wv    = (const float*)d_in[5];
  const float* W1    = (const float*)d_in[6];
  const float* b1    = (const float*)d_in[7];
  const float* W2    = (const float*)d_in[8];
  const float* b2    = (const float*)d_in[9];
  const float* Wo    = (const float*)d_in[10];
  const float* bo    = (const float*)d_in[11];
  const float* gamma = (const float*)d_in[12];
  const float* beta  = (const float*)d_in[13];

  const int QKV = NNODES * HIDDEN;            // 196608

  float*    ws   = (float*)d_ws;
  float*    qc   = ws;
  f16*      kTcH = (f16*)(qc + QKV);
  f16*      vcH  = kTcH + QKV;
  unsigned* WoP  = (unsigned*)(vcH + QKV);
  float*    P    = (float*)(WoP + 64 * 256);
  float*    b2m  = P + HIDDEN * 8;
  float*    pcx  = b2m + 8;
  float*    pcy  = pcx + NNODES;
  int*      vlist= (int*)(pcy + NNODES);
  int*      mlist= vlist + NNODES;
  int*      cnt  = mlist + NNODES;

  prep_kernel<<<NNODES / 4 + 4, 256, 0, stream>>>(
      nf, pos, mask, Wq, Wk, Wv, W1, b1, W2, b2, Wo,
      qc, kTcH, vcH, WoP, P, b2m, pcx, pcy, vlist, mlist, cnt);
  attn_kernel<<<NNODES, 256, 0, stream>>>(
      pcx, pcy, cnt, vlist, mlist, P, b2m, qc, kTcH, vcH, WoP,
      nf, bo, gamma, beta, (float*)d_out);
}